// Round 2
// baseline (947.004 us; speedup 1.0000x reference)
//
#include <hip/hip_runtime.h>
#include <hip/hip_bf16.h>

// Problem constants
#define B_  4
#define S_  2048
#define D_  256
#define H_  8
#define HD_ 32
#define K_  204          // int(2048 * 0.1)
#define SCALE_ 0.17677669529663687f  // 1/sqrt(32)

// ---- workspace layout (float offsets) ----
#define OFF_IMP    0          // 8192 floats: importance logits [B,S]
#define OFF_KG     8192       // 4*8*204*32 = 208896 floats [B,H,K,hd]
#define OFF_VG     217088     // 208896 floats
#define OFF_FLAGS  425984     // 8192 ints
#define OFF_KIDX   434176     // 1024 ints [B,K]
// total ~435200 floats = 1.74 MB

// ---------------- kernel 1: gate MLP -> importance logit per token ----------------
// one 64-thread block (1 wave) per token; sigmoid skipped (strictly monotone, ranking only;
// gate_b2 is a shared constant -> does not affect ordering)
__global__ __launch_bounds__(64) void gate_kernel(
    const float* __restrict__ x, const float* __restrict__ gw1,
    const float* __restrict__ gb1, const float* __restrict__ gw2, float* ws)
{
    const int token = blockIdx.x;          // 0..B*S-1
    const int tid = threadIdx.x;           // 0..63
    __shared__ __align__(16) float xs[D_];

    ((float4*)xs)[tid] = ((const float4*)(x + (size_t)token * D_))[tid];
    __syncthreads();

    const float4* wr = (const float4*)(gw1 + tid * D_);
    const float4* xr = (const float4*)xs;
    float acc = gb1[tid];
    #pragma unroll 8
    for (int i = 0; i < D_/4; ++i) {
        float4 w = wr[i]; float4 xv = xr[i];
        acc += w.x*xv.x + w.y*xv.y + w.z*xv.z + w.w*xv.w;
    }
    float h = fmaxf(acc, 0.0f);
    float p = h * gw2[tid];
    #pragma unroll
    for (int off = 32; off > 0; off >>= 1) p += __shfl_down(p, off);
    if (tid == 0) ws[OFF_IMP + token] = p;
}

// ---------------- kernel 2a: exact rank -> kept flag (matches lax.top_k ties) ----------------
// rank(i) = #{j: v_j > v_i} + #{j<i: v_j == v_i}; keep iff rank < K
__global__ __launch_bounds__(256) void rank_kernel(const float* __restrict__ ws_imp, int* flags)
{
    const int b = blockIdx.x >> 3;
    const int i = (blockIdx.x & 7) * 256 + threadIdx.x;   // element in batch
    __shared__ __align__(16) float vs[S_];
    const float* src = ws_imp + b * S_;
    #pragma unroll
    for (int c = 0; c < S_/256; ++c) vs[threadIdx.x + c*256] = src[threadIdx.x + c*256];
    __syncthreads();

    const float vi = vs[i];
    int gt = 0, eq = 0;
    const float4* v4 = (const float4*)vs;
    for (int j4 = 0; j4 < S_/4; ++j4) {
        float4 w = v4[j4];
        int base = j4 * 4;
        gt += (w.x > vi); eq += (w.x == vi) && (base + 0 < i);
        gt += (w.y > vi); eq += (w.y == vi) && (base + 1 < i);
        gt += (w.z > vi); eq += (w.z == vi) && (base + 2 < i);
        gt += (w.w > vi); eq += (w.w == vi) && (base + 3 < i);
    }
    flags[b * S_ + i] = ((gt + eq) < K_) ? 1 : 0;
}

// ---------------- kernel 2b: scan flags -> compact sorted index list ----------------
__global__ __launch_bounds__(256) void emit_kernel(const int* __restrict__ flags, int* kidx)
{
    const int b = blockIdx.x;
    const int t = threadIdx.x;
    __shared__ int fl[S_];
    __shared__ int cs[256];
    const int* src = flags + b * S_;
    #pragma unroll
    for (int c = 0; c < S_/256; ++c) fl[t + c*256] = src[t + c*256];
    __syncthreads();

    int s = 0;
    #pragma unroll
    for (int c = 0; c < 8; ++c) s += fl[t*8 + c];
    cs[t] = s;
    __syncthreads();
    // Hillis-Steele inclusive scan over 256 chunk sums
    for (int off = 1; off < 256; off <<= 1) {
        int v = (t >= off) ? cs[t - off] : 0;
        __syncthreads();
        cs[t] += v;
        __syncthreads();
    }
    int pos = cs[t] - s;   // exclusive prefix
    #pragma unroll
    for (int c = 0; c < 8; ++c) {
        int idx = t*8 + c;
        if (fl[idx]) { if (pos < K_) kidx[b * K_ + pos] = idx; ++pos; }
    }
}

// ---------------- kernel 3: K/V projection for kept keys only ----------------
// grid (K, B) x 256 threads; outputs Kg/Vg in [B,H,K,hd] fp32
__global__ __launch_bounds__(256) void kv_kernel(
    const float* __restrict__ x, const float* __restrict__ w_in,
    const float* __restrict__ b_in, float* ws, const int* __restrict__ kidx)
{
    const int b = blockIdx.y, j = blockIdx.x, tid = threadIdx.x;
    int tok = kidx[b * K_ + j];
    tok = min(max(tok, 0), S_ - 1);   // safety clamp (no-op when top-k count is exact)
    __shared__ __align__(16) float xs[D_];
    xs[tid] = x[((size_t)b * S_ + tok) * D_ + tid];
    __syncthreads();

    const int eK = D_ + tid, eV = 2*D_ + tid;
    float accK = b_in[eK];
    float accV = b_in[eV];
    const float4* wK = (const float4*)(w_in + (size_t)eK * D_);
    const float4* wV = (const float4*)(w_in + (size_t)eV * D_);
    const float4* xr = (const float4*)xs;
    #pragma unroll 8
    for (int i = 0; i < D_/4; ++i) {
        float4 xv = xr[i];
        float4 a = wK[i]; accK += a.x*xv.x + a.y*xv.y + a.z*xv.z + a.w*xv.w;
        float4 c = wV[i]; accV += c.x*xv.x + c.y*xv.y + c.z*xv.z + c.w*xv.w;
    }
    const int h = tid >> 5, d = tid & 31;
    const int o = ((b * H_ + h) * K_ + j) * HD_ + d;
    ws[OFF_KG + o] = accK;
    ws[OFF_VG + o] = accV;
}

// ---------------- kernel 4: fused Q-proj + masked MHA + out-proj ----------------
// grid (S/8, B) x 256 threads; 8 queries per block
#define TQ_ 8
#define SP_ 208   // padded score stride
__global__ __launch_bounds__(256) void attn_kernel(
    const float* __restrict__ x, const float* __restrict__ w_in,
    const float* __restrict__ b_in, const float* __restrict__ w_out,
    const float* __restrict__ b_out, const float* __restrict__ ws, float* out)
{
    const int b = blockIdx.y;
    const int q0 = blockIdx.x * TQ_;
    const int tid = threadIdx.x;

    __shared__ __align__(16) float xs[TQ_ * D_];   // reused as attn output after q-proj
    __shared__ __align__(16) float qs[TQ_ * D_];
    __shared__ __align__(16) float ss[TQ_ * SP_];
    __shared__ float red[TQ_ * 32];
    __shared__ float msum[TQ_], lsum[TQ_];

    // load 8 queries' x (2048 floats): two float4 per thread
    {
        const float4* src = (const float4*)(x + ((size_t)b * S_ + q0) * D_);
        float4* dst = (float4*)xs;
        dst[tid] = src[tid];
        dst[tid + 256] = src[tid + 256];
    }
    __syncthreads();

    // Q projection: thread = output feature e, iterate over 8 queries
    {
        const int e = tid;
        const float4* wr = (const float4*)(w_in + (size_t)e * D_);
        const float bias = b_in[e];
        #pragma unroll
        for (int qi = 0; qi < TQ_; ++qi) {
            const float4* xr = (const float4*)(xs + qi * D_);
            float acc = bias;
            #pragma unroll 8
            for (int dd = 0; dd < D_/4; ++dd) {
                float4 w = wr[dd]; float4 xv = xr[dd];
                acc += w.x*xv.x + w.y*xv.y + w.z*xv.z + w.w*xv.w;
            }
            qs[qi * D_ + e] = acc;
        }
    }
    __syncthreads();

    float* attn = xs;  // alias: x tile no longer needed
    const int qi = tid >> 5, ln = tid & 31;

    for (int h = 0; h < H_; ++h) {
        // scores for kept keys
        float4 qreg[8];
        {
            const float4* qrow = (const float4*)(qs + qi * D_ + h * HD_);
            #pragma unroll
            for (int c = 0; c < 8; ++c) qreg[c] = qrow[c];
        }
        const float* kg = ws + OFF_KG + (b * H_ + h) * (K_ * HD_);
        for (int j = ln; j < K_; j += 32) {
            const float4* kr = (const float4*)(kg + j * HD_);
            float acc = 0.0f;
            #pragma unroll
            for (int c = 0; c < 8; ++c) {
                float4 kv = kr[c];
                acc += qreg[c].x*kv.x + qreg[c].y*kv.y + qreg[c].z*kv.z + qreg[c].w*kv.w;
            }
            ss[qi * SP_ + j] = acc * SCALE_;
        }
        __syncthreads();

        // softmax max
        float m = -3.4e38f;
        for (int j = ln; j < K_; j += 32) m = fmaxf(m, ss[qi * SP_ + j]);
        red[tid] = m;
        __syncthreads();
        if (tid < TQ_) {
            float mm = red[tid * 32];
            for (int c = 1; c < 32; ++c) mm = fmaxf(mm, red[tid * 32 + c]);
            msum[tid] = mm;
        }
        __syncthreads();
        // exp + sum
        const float mq = msum[qi];
        float p = 0.0f;
        for (int j = ln; j < K_; j += 32) {
            float e = __expf(ss[qi * SP_ + j] - mq);
            ss[qi * SP_ + j] = e;
            p += e;
        }
        red[tid] = p;
        __syncthreads();
        if (tid < TQ_) {
            float sum = 0.0f;
            for (int c = 0; c < 32; ++c) sum += red[tid * 32 + c];
            lsum[tid] = sum;
        }
        __syncthreads();

        // PV: thread = (qi, d=ln)
        {
            const float* vg = ws + OFF_VG + (b * H_ + h) * (K_ * HD_) + ln;
            float acc = 0.0f;
            const float* sr = ss + qi * SP_;
            for (int j = 0; j < K_; ++j) acc += sr[j] * vg[j * HD_];
            attn[qi * D_ + h * HD_ + ln] = acc / lsum[qi];
        }
        __syncthreads();
    }

    // out projection: thread = output feature o, iterate over 8 queries
    {
        const int o = tid;
        const float4* wr = (const float4*)(w_out + (size_t)o * D_);
        const float bias = b_out[o];
        #pragma unroll
        for (int q = 0; q < TQ_; ++q) {
            const float4* ar = (const float4*)(attn + q * D_);
            float acc = bias;
            #pragma unroll 8
            for (int dd = 0; dd < D_/4; ++dd) {
                float4 w = wr[dd]; float4 av = ar[dd];
                acc += w.x*av.x + w.y*av.y + w.z*av.z + w.w*av.w;
            }
            out[((size_t)b * S_ + q0 + q) * D_ + o] = acc;
        }
    }
}

extern "C" void kernel_launch(void* const* d_in, const int* in_sizes, int n_in,
                              void* d_out, int out_size, void* d_ws, size_t ws_size,
                              hipStream_t stream)
{
    const float* x     = (const float*)d_in[0];
    const float* w_in  = (const float*)d_in[1];
    const float* b_in  = (const float*)d_in[2];
    const float* w_out = (const float*)d_in[3];
    const float* b_out = (const float*)d_in[4];
    const float* gw1   = (const float*)d_in[5];
    const float* gb1   = (const float*)d_in[6];
    const float* gw2   = (const float*)d_in[7];
    // d_in[8] = gate_b2: constant inside a monotone sigmoid -> does not affect top-k

    float* ws = (float*)d_ws;
    int* flags = (int*)(ws + OFF_FLAGS);
    int* kidx  = (int*)(ws + OFF_KIDX);
    float* out = (float*)d_out;

    gate_kernel<<<B_ * S_, 64, 0, stream>>>(x, gw1, gb1, gw2, ws);
    rank_kernel<<<B_ * 8, 256, 0, stream>>>(ws + OFF_IMP, flags);
    emit_kernel<<<B_, 256, 0, stream>>>(flags, kidx);
    kv_kernel<<<dim3(K_, B_), 256, 0, stream>>>(x, w_in, b_in, ws, kidx);
    attn_kernel<<<dim3(S_ / TQ_, B_), 256, 0, stream>>>(x, w_in, b_in, w_out, b_out, ws, out);
}

// Round 3
// 624.676 us; speedup vs baseline: 1.5160x; 1.5160x over previous
//
#include <hip/hip_runtime.h>
#include <hip/hip_bf16.h>

// Problem constants
#define B_  4
#define S_  2048
#define D_  256
#define H_  8
#define HD_ 32
#define K_  204          // int(2048 * 0.1)
#define SCALE_ 0.17677669529663687f  // 1/sqrt(32)

// ---- workspace layout (float offsets) ----
#define OFF_IMP    0          // 8192 floats: importance logits [B,S]
#define OFF_KG     8192       // 4*8*204*32 = 208896 floats [B,H,K,hd]
#define OFF_VG     217088     // 208896 floats
#define OFF_FLAGS  425984     // 8192 ints
#define OFF_KIDX   434176     // 1024 ints [B,K]

// ---------------- kernel 1: gate MLP -> importance logit ----------------
// 8 tokens per 256-thread block. thread = (f = tid>>2 in [0,64), c = tid&3 d-quarter).
// 4 consecutive lanes read 64B-contiguous weight chunks (coalesced); weight regs
// reused across all 8 tokens. sigmoid/gate_b2 skipped (monotone, ranking only).
__global__ __launch_bounds__(256) void gate_kernel(
    const float* __restrict__ x, const float* __restrict__ gw1,
    const float* __restrict__ gb1, const float* __restrict__ gw2, float* ws)
{
    const int t0 = blockIdx.x * 8;
    const int tid = threadIdx.x;
    __shared__ __align__(16) float xs[8 * D_];
    __shared__ float hred[8 * 64];

    const float4* src = (const float4*)(x + (size_t)t0 * D_);
    ((float4*)xs)[tid]       = src[tid];
    ((float4*)xs)[tid + 256] = src[tid + 256];
    __syncthreads();

    const int c = tid & 3, f = tid >> 2;
    float4 wv[16];
    const float4* wr = (const float4*)(gw1 + (size_t)f * D_) + c;
    #pragma unroll
    for (int j = 0; j < 16; ++j) wv[j] = wr[j * 4];
    const float bb = gb1[f], g2 = gw2[f];

    #pragma unroll
    for (int tk = 0; tk < 8; ++tk) {
        const float4* xr = (const float4*)(xs + tk * D_) + c;
        float a = 0.0f;
        #pragma unroll
        for (int j = 0; j < 16; ++j) {
            float4 xv = xr[j * 4];
            a += wv[j].x*xv.x + wv[j].y*xv.y + wv[j].z*xv.z + wv[j].w*xv.w;
        }
        a += __shfl_xor(a, 1);
        a += __shfl_xor(a, 2);
        if (c == 0) hred[tk * 64 + f] = fmaxf(a + bb, 0.0f) * g2;
    }
    __syncthreads();

    const int tk = tid >> 5, ln = tid & 31;
    float s = hred[tk * 64 + ln] + hred[tk * 64 + ln + 32];
    #pragma unroll
    for (int o = 16; o; o >>= 1) s += __shfl_xor(s, o, 32);
    if (ln == 0) ws[OFF_IMP + t0 + tk] = s;
}

// ---------------- kernel 2a: exact rank -> kept flag (lax.top_k ties) ----------------
__global__ __launch_bounds__(256) void rank_kernel(const float* __restrict__ ws_imp, int* flags)
{
    const int b = blockIdx.x >> 3;
    const int i = (blockIdx.x & 7) * 256 + threadIdx.x;
    __shared__ __align__(16) float vs[S_];
    const float* src = ws_imp + b * S_;
    #pragma unroll
    for (int c = 0; c < S_/256; ++c) vs[threadIdx.x + c*256] = src[threadIdx.x + c*256];
    __syncthreads();

    const float vi = vs[i];
    int gt = 0, eq = 0;
    const float4* v4 = (const float4*)vs;
    for (int j4 = 0; j4 < S_/4; ++j4) {
        float4 w = v4[j4];
        int base = j4 * 4;
        gt += (w.x > vi); eq += (w.x == vi) && (base + 0 < i);
        gt += (w.y > vi); eq += (w.y == vi) && (base + 1 < i);
        gt += (w.z > vi); eq += (w.z == vi) && (base + 2 < i);
        gt += (w.w > vi); eq += (w.w == vi) && (base + 3 < i);
    }
    flags[b * S_ + i] = ((gt + eq) < K_) ? 1 : 0;
}

// ---------------- kernel 2b: scan flags -> compact sorted index list ----------------
__global__ __launch_bounds__(256) void emit_kernel(const int* __restrict__ flags, int* kidx)
{
    const int b = blockIdx.x;
    const int t = threadIdx.x;
    __shared__ int fl[S_];
    __shared__ int cs[256];
    const int* src = flags + b * S_;
    #pragma unroll
    for (int c = 0; c < S_/256; ++c) fl[t + c*256] = src[t + c*256];
    __syncthreads();

    int s = 0;
    #pragma unroll
    for (int c = 0; c < 8; ++c) s += fl[t*8 + c];
    cs[t] = s;
    __syncthreads();
    for (int off = 1; off < 256; off <<= 1) {
        int v = (t >= off) ? cs[t - off] : 0;
        __syncthreads();
        cs[t] += v;
        __syncthreads();
    }
    int pos = cs[t] - s;
    #pragma unroll
    for (int c = 0; c < 8; ++c) {
        int idx = t*8 + c;
        if (fl[idx]) { if (pos < K_) kidx[b * K_ + pos] = idx; ++pos; }
    }
}

// ---------------- kernel 3: K/V projection for kept keys ----------------
// 4 keys per block, grid (51, B). thread = (f, c) coalesced weight reads + shfl reduce.
__global__ __launch_bounds__(256) void kv_kernel(
    const float* __restrict__ x, const float* __restrict__ w_in,
    const float* __restrict__ b_in, float* ws, const int* __restrict__ kidx)
{
    const int b = blockIdx.y, j0 = blockIdx.x * 4, tid = threadIdx.x;
    __shared__ __align__(16) float xs[4 * D_];
    __shared__ int toks[4];
    if (tid < 4) {
        int tk = kidx[b * K_ + j0 + tid];
        toks[tid] = min(max(tk, 0), S_ - 1);
    }
    __syncthreads();
    {
        const int kk = tid >> 6, l = tid & 63;
        ((float4*)xs)[kk * 64 + l] =
            ((const float4*)(x + ((size_t)b * S_ + toks[kk]) * D_))[l];
    }
    __syncthreads();

    const int c = tid & 3, f = tid >> 2;
    #pragma unroll 1
    for (int fg = 0; fg < 8; ++fg) {
        const int eh = fg * 64 + f;            // 0..511 over K then V features
        float4 wv[16];
        const float4* wr = (const float4*)(w_in + (size_t)(D_ + eh) * D_) + c;
        #pragma unroll
        for (int j = 0; j < 16; ++j) wv[j] = wr[j * 4];
        float a0 = 0, a1 = 0, a2 = 0, a3 = 0;
        #pragma unroll
        for (int j = 0; j < 16; ++j) {
            float4 w = wv[j];
            float4 x0 = ((const float4*)(xs + 0*D_))[c + j*4];
            float4 x1 = ((const float4*)(xs + 1*D_))[c + j*4];
            float4 x2 = ((const float4*)(xs + 2*D_))[c + j*4];
            float4 x3 = ((const float4*)(xs + 3*D_))[c + j*4];
            a0 += w.x*x0.x + w.y*x0.y + w.z*x0.z + w.w*x0.w;
            a1 += w.x*x1.x + w.y*x1.y + w.z*x1.z + w.w*x1.w;
            a2 += w.x*x2.x + w.y*x2.y + w.z*x2.z + w.w*x2.w;
            a3 += w.x*x3.x + w.y*x3.y + w.z*x3.z + w.w*x3.w;
        }
        a0 += __shfl_xor(a0, 1); a0 += __shfl_xor(a0, 2);
        a1 += __shfl_xor(a1, 1); a1 += __shfl_xor(a1, 2);
        a2 += __shfl_xor(a2, 1); a2 += __shfl_xor(a2, 2);
        a3 += __shfl_xor(a3, 1); a3 += __shfl_xor(a3, 2);
        if (c == 0) {
            const float bias = b_in[D_ + eh];
            const int isV = eh >> 8;
            const int ee = eh & 255;
            const int h = ee >> 5, d = ee & 31;
            float* dst = ws + (isV ? OFF_VG : OFF_KG) + ((b * H_ + h) * K_) * HD_ + d;
            dst[(j0 + 0) * HD_] = a0 + bias;
            dst[(j0 + 1) * HD_] = a1 + bias;
            dst[(j0 + 2) * HD_] = a2 + bias;
            dst[(j0 + 3) * HD_] = a3 + bias;
        }
    }
}

// ---------------- kernel 4: fused Q-proj + masked MHA + out-proj ----------------
#define TQ_ 8
#define SP_ 208
__global__ __launch_bounds__(256) void attn_kernel(
    const float* __restrict__ x, const float* __restrict__ w_in,
    const float* __restrict__ b_in, const float* __restrict__ w_out,
    const float* __restrict__ b_out, const float* __restrict__ ws, float* out)
{
    const int b = blockIdx.y;
    const int q0 = blockIdx.x * TQ_;
    const int tid = threadIdx.x;

    __shared__ __align__(16) float xs[TQ_ * D_];   // x tile; reused as attn output
    __shared__ __align__(16) float qs[TQ_ * D_];
    __shared__ __align__(16) float ss[2 * TQ_ * SP_];

    // ---- load 8 queries' x ----
    {
        const float4* src = (const float4*)(x + ((size_t)b * S_ + q0) * D_);
        ((float4*)xs)[tid]       = src[tid];
        ((float4*)xs)[tid + 256] = src[tid + 256];
    }
    __syncthreads();

    // ---- Q projection: thread = (f, c), coalesced weights, shfl reduce ----
    {
        const int c = tid & 3, f = tid >> 2;
        #pragma unroll 1
        for (int fg = 0; fg < 4; ++fg) {
            const int e = fg * 64 + f;
            float4 wv[16];
            const float4* wr = (const float4*)(w_in + (size_t)e * D_) + c;
            #pragma unroll
            for (int j = 0; j < 16; ++j) wv[j] = wr[j * 4];
            const float bias = b_in[e];
            #pragma unroll
            for (int q = 0; q < TQ_; ++q) {
                const float4* xr = (const float4*)(xs + q * D_) + c;
                float a = 0.0f;
                #pragma unroll
                for (int j = 0; j < 16; ++j) {
                    float4 xv = xr[j * 4];
                    a += wv[j].x*xv.x + wv[j].y*xv.y + wv[j].z*xv.z + wv[j].w*xv.w;
                }
                a += __shfl_xor(a, 1);
                a += __shfl_xor(a, 2);
                if (c == 0) qs[q * D_ + e] = a + bias;
            }
        }
    }
    __syncthreads();

    float* attnO = xs;
    const int qi = tid >> 5, ln = tid & 31;
    const int nk = (ln < 12) ? 7 : 6;   // keys j = ln + 32t, j < 204

    // ---- head-pair loop: scores in regs, shuffle softmax, coalesced PV ----
    #pragma unroll 1
    for (int hp = 0; hp < 4; ++hp) {
        const int hA = hp, hB = hp + 4;
        float4 qA[8], qB[8];
        {
            const float4* qra = (const float4*)(qs + qi * D_ + hA * HD_);
            const float4* qrb = (const float4*)(qs + qi * D_ + hB * HD_);
            #pragma unroll
            for (int c = 0; c < 8; ++c) { qA[c] = qra[c]; qB[c] = qrb[c]; }
        }
        const float* kgA = ws + OFF_KG + ((b * H_ + hA) * K_) * HD_;
        const float* kgB = ws + OFF_KG + ((b * H_ + hB) * K_) * HD_;

        float scA[7], scB[7];
        for (int t = 0; t < nk; ++t) {
            const int j = ln + 32 * t;
            const float4* ka = (const float4*)(kgA + j * HD_);
            const float4* kb = (const float4*)(kgB + j * HD_);
            float aA = 0.0f, aB = 0.0f;
            #pragma unroll
            for (int c = 0; c < 8; ++c) {
                float4 k4 = ka[c];
                aA += qA[c].x*k4.x + qA[c].y*k4.y + qA[c].z*k4.z + qA[c].w*k4.w;
                float4 l4 = kb[c];
                aB += qB[c].x*l4.x + qB[c].y*l4.y + qB[c].z*l4.z + qB[c].w*l4.w;
            }
            scA[t] = aA * SCALE_;
            scB[t] = aB * SCALE_;
        }

        // softmax over 204 keys: per-thread partials + width-32 shuffles
        float mA = -3.4e38f, mB = -3.4e38f;
        for (int t = 0; t < nk; ++t) { mA = fmaxf(mA, scA[t]); mB = fmaxf(mB, scB[t]); }
        #pragma unroll
        for (int o = 16; o; o >>= 1) {
            mA = fmaxf(mA, __shfl_xor(mA, o, 32));
            mB = fmaxf(mB, __shfl_xor(mB, o, 32));
        }
        float lA = 0.0f, lB = 0.0f;
        for (int t = 0; t < nk; ++t) {
            float eA = __expf(scA[t] - mA); scA[t] = eA; lA += eA;
            float eB = __expf(scB[t] - mB); scB[t] = eB; lB += eB;
        }
        #pragma unroll
        for (int o = 16; o; o >>= 1) {
            lA += __shfl_xor(lA, o, 32);
            lB += __shfl_xor(lB, o, 32);
        }
        const float iA = 1.0f / lA, iB = 1.0f / lB;

        float* sA = ss + qi * SP_;
        float* sB = ss + (TQ_ + qi) * SP_;
        for (int t = 0; t < nk; ++t) {
            sA[ln + 32 * t] = scA[t];
            sB[ln + 32 * t] = scB[t];
        }
        __syncthreads();

        // PV: thread = (qi, d=ln); V reads lane-coalesced; 8 indep chains
        const float* vA = ws + OFF_VG + ((b * H_ + hA) * K_) * HD_ + ln;
        const float* vB = ws + OFF_VG + ((b * H_ + hB) * K_) * HD_ + ln;
        float a0=0,a1=0,a2=0,a3=0,c0=0,c1=0,c2=0,c3=0;
        for (int j = 0; j < K_; j += 4) {
            a0 += sA[j+0] * vA[(j+0)*HD_];
            a1 += sA[j+1] * vA[(j+1)*HD_];
            a2 += sA[j+2] * vA[(j+2)*HD_];
            a3 += sA[j+3] * vA[(j+3)*HD_];
            c0 += sB[j+0] * vB[(j+0)*HD_];
            c1 += sB[j+1] * vB[(j+1)*HD_];
            c2 += sB[j+2] * vB[(j+2)*HD_];
            c3 += sB[j+3] * vB[(j+3)*HD_];
        }
        attnO[qi * D_ + hA * HD_ + ln] = ((a0+a1)+(a2+a3)) * iA;
        attnO[qi * D_ + hB * HD_ + ln] = ((c0+c1)+(c2+c3)) * iB;
        __syncthreads();
    }

    // ---- out projection: thread = (f, c), coalesced weights, shfl reduce ----
    {
        const int c = tid & 3, f = tid >> 2;
        #pragma unroll 1
        for (int fg = 0; fg < 4; ++fg) {
            const int o = fg * 64 + f;
            float4 wv[16];
            const float4* wr = (const float4*)(w_out + (size_t)o * D_) + c;
            #pragma unroll
            for (int j = 0; j < 16; ++j) wv[j] = wr[j * 4];
            const float bias = b_out[o];
            #pragma unroll
            for (int q = 0; q < TQ_; ++q) {
                const float4* ar = (const float4*)(attnO + q * D_) + c;
                float a = 0.0f;
                #pragma unroll
                for (int j = 0; j < 16; ++j) {
                    float4 av = ar[j * 4];
                    a += wv[j].x*av.x + wv[j].y*av.y + wv[j].z*av.z + wv[j].w*av.w;
                }
                a += __shfl_xor(a, 1);
                a += __shfl_xor(a, 2);
                if (c == 0) out[((size_t)b * S_ + q0 + q) * D_ + o] = a + bias;
            }
        }
    }
}

extern "C" void kernel_launch(void* const* d_in, const int* in_sizes, int n_in,
                              void* d_out, int out_size, void* d_ws, size_t ws_size,
                              hipStream_t stream)
{
    const float* x     = (const float*)d_in[0];
    const float* w_in  = (const float*)d_in[1];
    const float* b_in  = (const float*)d_in[2];
    const float* w_out = (const float*)d_in[3];
    const float* b_out = (const float*)d_in[4];
    const float* gw1   = (const float*)d_in[5];
    const float* gb1   = (const float*)d_in[6];
    const float* gw2   = (const float*)d_in[7];
    // d_in[8] = gate_b2: constant inside a monotone sigmoid -> doesn't affect top-k

    float* ws = (float*)d_ws;
    int* flags = (int*)(ws + OFF_FLAGS);
    int* kidx  = (int*)(ws + OFF_KIDX);
    float* out = (float*)d_out;

    gate_kernel<<<B_ * S_ / 8, 256, 0, stream>>>(x, gw1, gb1, gw2, ws);
    rank_kernel<<<B_ * 8, 256, 0, stream>>>(ws + OFF_IMP, flags);
    emit_kernel<<<B_, 256, 0, stream>>>(flags, kidx);
    kv_kernel<<<dim3(51, B_), 256, 0, stream>>>(x, w_in, b_in, ws, kidx);
    attn_kernel<<<dim3(S_ / TQ_, B_), 256, 0, stream>>>(x, w_in, b_in, w_out, b_out, ws, out);
}

// Round 4
// 246.804 us; speedup vs baseline: 3.8371x; 2.5311x over previous
//
#include <hip/hip_runtime.h>
#include <hip/hip_bf16.h>

// Problem constants
#define B_  4
#define S_  2048
#define D_  256
#define H_  8
#define HD_ 32
#define K_  204          // int(2048 * 0.1)
#define SCALE_ 0.17677669529663687f  // 1/sqrt(32)

// ---- workspace layout (float offsets) ----
#define OFF_IMP    0          // 8192 floats
#define OFF_KG     8192       // 208896 floats [B,H,K,hd]
#define OFF_VG     217088     // 208896 floats
#define OFF_FLAGS  425984     // 8192 ints
#define OFF_KIDX   434176     // 1024 ints
#define OFF_Q      435200     // 2097152 floats [B*S, D]
#define OFF_AO     2532352    // 2097152 floats [B*S, D]
// total ~4.63M floats = 18.5 MB

// ---------------- kernel 1: gate MLP -> importance logit ----------------
__global__ __launch_bounds__(256) void gate_kernel(
    const float* __restrict__ x, const float* __restrict__ gw1,
    const float* __restrict__ gb1, const float* __restrict__ gw2, float* ws)
{
    const int t0 = blockIdx.x * 8;
    const int tid = threadIdx.x;
    __shared__ __align__(16) float xs[8 * D_];
    __shared__ float hred[8 * 64];

    const float4* src = (const float4*)(x + (size_t)t0 * D_);
    ((float4*)xs)[tid]       = src[tid];
    ((float4*)xs)[tid + 256] = src[tid + 256];
    __syncthreads();

    const int c = tid & 3, f = tid >> 2;
    float4 wv[16];
    const float4* wr = (const float4*)(gw1 + (size_t)f * D_) + c;
    #pragma unroll
    for (int j = 0; j < 16; ++j) wv[j] = wr[j * 4];
    const float bb = gb1[f], g2 = gw2[f];

    #pragma unroll
    for (int tk = 0; tk < 8; ++tk) {
        const float4* xr = (const float4*)(xs + tk * D_) + c;
        float a = 0.0f;
        #pragma unroll
        for (int j = 0; j < 16; ++j) {
            float4 xv = xr[j * 4];
            a += wv[j].x*xv.x + wv[j].y*xv.y + wv[j].z*xv.z + wv[j].w*xv.w;
        }
        a += __shfl_xor(a, 1);
        a += __shfl_xor(a, 2);
        if (c == 0) hred[tk * 64 + f] = fmaxf(a + bb, 0.0f) * g2;
    }
    __syncthreads();

    const int tk = tid >> 5, ln = tid & 31;
    float s = hred[tk * 64 + ln] + hred[tk * 64 + ln + 32];
    #pragma unroll
    for (int o = 16; o; o >>= 1) s += __shfl_xor(s, o, 32);
    if (ln == 0) ws[OFF_IMP + t0 + tk] = s;
}

// ---------------- kernel 2a: exact rank -> kept flag (lax.top_k ties) ----------------
__global__ __launch_bounds__(256) void rank_kernel(const float* __restrict__ ws_imp, int* flags)
{
    const int b = blockIdx.x >> 3;
    const int i = (blockIdx.x & 7) * 256 + threadIdx.x;
    __shared__ __align__(16) float vs[S_];
    const float* src = ws_imp + b * S_;
    #pragma unroll
    for (int c = 0; c < S_/256; ++c) vs[threadIdx.x + c*256] = src[threadIdx.x + c*256];
    __syncthreads();

    const float vi = vs[i];
    int gt = 0, eq = 0;
    const float4* v4 = (const float4*)vs;
    for (int j4 = 0; j4 < S_/4; ++j4) {
        float4 w = v4[j4];
        int base = j4 * 4;
        gt += (w.x > vi); eq += (w.x == vi) && (base + 0 < i);
        gt += (w.y > vi); eq += (w.y == vi) && (base + 1 < i);
        gt += (w.z > vi); eq += (w.z == vi) && (base + 2 < i);
        gt += (w.w > vi); eq += (w.w == vi) && (base + 3 < i);
    }
    flags[b * S_ + i] = ((gt + eq) < K_) ? 1 : 0;
}

// ---------------- kernel 2b: scan flags -> compact sorted index list ----------------
__global__ __launch_bounds__(256) void emit_kernel(const int* __restrict__ flags, int* kidx)
{
    const int b = blockIdx.x;
    const int t = threadIdx.x;
    __shared__ int fl[S_];
    __shared__ int cs[256];
    const int* src = flags + b * S_;
    #pragma unroll
    for (int c = 0; c < S_/256; ++c) fl[t + c*256] = src[t + c*256];
    __syncthreads();

    int s = 0;
    #pragma unroll
    for (int c = 0; c < 8; ++c) s += fl[t*8 + c];
    cs[t] = s;
    __syncthreads();
    for (int off = 1; off < 256; off <<= 1) {
        int v = (t >= off) ? cs[t - off] : 0;
        __syncthreads();
        cs[t] += v;
        __syncthreads();
    }
    int pos = cs[t] - s;
    #pragma unroll
    for (int c = 0; c < 8; ++c) {
        int idx = t*8 + c;
        if (fl[idx]) { if (pos < K_) kidx[b * K_ + pos] = idx; ++pos; }
    }
}

// ---------------- kernel 3: K/V projection for kept keys ----------------
__global__ __launch_bounds__(256) void kv_kernel(
    const float* __restrict__ x, const float* __restrict__ w_in,
    const float* __restrict__ b_in, float* ws, const int* __restrict__ kidx)
{
    const int b = blockIdx.y, j0 = blockIdx.x * 4, tid = threadIdx.x;
    __shared__ __align__(16) float xs[4 * D_];
    __shared__ int toks[4];
    if (tid < 4) {
        int tk = kidx[b * K_ + j0 + tid];
        toks[tid] = min(max(tk, 0), S_ - 1);
    }
    __syncthreads();
    {
        const int kk = tid >> 6, l = tid & 63;
        ((float4*)xs)[kk * 64 + l] =
            ((const float4*)(x + ((size_t)b * S_ + toks[kk]) * D_))[l];
    }
    __syncthreads();

    const int c = tid & 3, f = tid >> 2;
    #pragma unroll 1
    for (int fg = 0; fg < 8; ++fg) {
        const int eh = fg * 64 + f;
        float4 wv[16];
        const float4* wr = (const float4*)(w_in + (size_t)(D_ + eh) * D_) + c;
        #pragma unroll
        for (int j = 0; j < 16; ++j) wv[j] = wr[j * 4];
        float a0 = 0, a1 = 0, a2 = 0, a3 = 0;
        #pragma unroll
        for (int j = 0; j < 16; ++j) {
            float4 w = wv[j];
            float4 x0 = ((const float4*)(xs + 0*D_))[c + j*4];
            float4 x1 = ((const float4*)(xs + 1*D_))[c + j*4];
            float4 x2 = ((const float4*)(xs + 2*D_))[c + j*4];
            float4 x3 = ((const float4*)(xs + 3*D_))[c + j*4];
            a0 += w.x*x0.x + w.y*x0.y + w.z*x0.z + w.w*x0.w;
            a1 += w.x*x1.x + w.y*x1.y + w.z*x1.z + w.w*x1.w;
            a2 += w.x*x2.x + w.y*x2.y + w.z*x2.z + w.w*x2.w;
            a3 += w.x*x3.x + w.y*x3.y + w.z*x3.z + w.w*x3.w;
        }
        a0 += __shfl_xor(a0, 1); a0 += __shfl_xor(a0, 2);
        a1 += __shfl_xor(a1, 1); a1 += __shfl_xor(a1, 2);
        a2 += __shfl_xor(a2, 1); a2 += __shfl_xor(a2, 2);
        a3 += __shfl_xor(a3, 1); a3 += __shfl_xor(a3, 2);
        if (c == 0) {
            const float bias = b_in[D_ + eh];
            const int isV = eh >> 8;
            const int ee = eh & 255;
            const int h = ee >> 5, d = ee & 31;
            float* dst = ws + (isV ? OFF_VG : OFF_KG) + ((b * H_ + h) * K_) * HD_ + d;
            dst[(j0 + 0) * HD_] = a0 + bias;
            dst[(j0 + 1) * HD_] = a1 + bias;
            dst[(j0 + 2) * HD_] = a2 + bias;
            dst[(j0 + 3) * HD_] = a3 + bias;
        }
    }
}

// ---------------- kernel 4: tiled fp32 GEMM  C[M,256] = A[M,256] * W[256,256]^T + bias ----------------
// W row-major [n][k] (torch Linear layout). BM=BN=64, BK=32, 4x4 microtile.
__global__ __launch_bounds__(256) void gemm_kernel(
    const float* __restrict__ A, const float* __restrict__ W,
    const float* __restrict__ bias, float* __restrict__ C)
{
    const int m0 = blockIdx.x * 64;
    const int n0 = blockIdx.y * 64;
    const int tid = threadIdx.x;
    __shared__ __align__(16) float As[32 * 68];
    __shared__ __align__(16) float Bs[32 * 68];
    const int tm = tid & 15, tn = tid >> 4;
    const int row = tid >> 3, dc = tid & 7;

    float4 acc0 = {0,0,0,0}, acc1 = {0,0,0,0}, acc2 = {0,0,0,0}, acc3 = {0,0,0,0};

    for (int k0 = 0; k0 < D_; k0 += 32) {
        float4 a0 = *(const float4*)(A + (size_t)(m0 + row) * D_ + k0 + dc * 4);
        float4 a1 = *(const float4*)(A + (size_t)(m0 + row + 32) * D_ + k0 + dc * 4);
        float4 w0 = *(const float4*)(W + (size_t)(n0 + row) * D_ + k0 + dc * 4);
        float4 w1 = *(const float4*)(W + (size_t)(n0 + row + 32) * D_ + k0 + dc * 4);
        __syncthreads();
        As[(dc*4+0)*68 + row] = a0.x; As[(dc*4+1)*68 + row] = a0.y;
        As[(dc*4+2)*68 + row] = a0.z; As[(dc*4+3)*68 + row] = a0.w;
        As[(dc*4+0)*68 + row+32] = a1.x; As[(dc*4+1)*68 + row+32] = a1.y;
        As[(dc*4+2)*68 + row+32] = a1.z; As[(dc*4+3)*68 + row+32] = a1.w;
        Bs[(dc*4+0)*68 + row] = w0.x; Bs[(dc*4+1)*68 + row] = w0.y;
        Bs[(dc*4+2)*68 + row] = w0.z; Bs[(dc*4+3)*68 + row] = w0.w;
        Bs[(dc*4+0)*68 + row+32] = w1.x; Bs[(dc*4+1)*68 + row+32] = w1.y;
        Bs[(dc*4+2)*68 + row+32] = w1.z; Bs[(dc*4+3)*68 + row+32] = w1.w;
        __syncthreads();
        #pragma unroll
        for (int k = 0; k < 32; ++k) {
            float4 a4 = *(const float4*)&As[k*68 + tm*4];
            float4 b4 = *(const float4*)&Bs[k*68 + tn*4];
            acc0.x += a4.x*b4.x; acc0.y += a4.x*b4.y; acc0.z += a4.x*b4.z; acc0.w += a4.x*b4.w;
            acc1.x += a4.y*b4.x; acc1.y += a4.y*b4.y; acc1.z += a4.y*b4.z; acc1.w += a4.y*b4.w;
            acc2.x += a4.z*b4.x; acc2.y += a4.z*b4.y; acc2.z += a4.z*b4.z; acc2.w += a4.z*b4.w;
            acc3.x += a4.w*b4.x; acc3.y += a4.w*b4.y; acc3.z += a4.w*b4.z; acc3.w += a4.w*b4.w;
        }
    }
    float4 bi = *(const float4*)(bias + n0 + tn*4);
    float4 o;
    o.x = acc0.x+bi.x; o.y = acc0.y+bi.y; o.z = acc0.z+bi.z; o.w = acc0.w+bi.w;
    *(float4*)(C + (size_t)(m0 + tm*4 + 0) * D_ + n0 + tn*4) = o;
    o.x = acc1.x+bi.x; o.y = acc1.y+bi.y; o.z = acc1.z+bi.z; o.w = acc1.w+bi.w;
    *(float4*)(C + (size_t)(m0 + tm*4 + 1) * D_ + n0 + tn*4) = o;
    o.x = acc2.x+bi.x; o.y = acc2.y+bi.y; o.z = acc2.z+bi.z; o.w = acc2.w+bi.w;
    *(float4*)(C + (size_t)(m0 + tm*4 + 2) * D_ + n0 + tn*4) = o;
    o.x = acc3.x+bi.x; o.y = acc3.y+bi.y; o.z = acc3.z+bi.z; o.w = acc3.w+bi.w;
    *(float4*)(C + (size_t)(m0 + tm*4 + 3) * D_ + n0 + tn*4) = o;
}

// ---------------- kernel 5: attention core ----------------
// one block per (32-query tile, head, batch). K/V/Q staged in LDS once.
__global__ __launch_bounds__(256) void attn_kernel(const float* __restrict__ ws, float* __restrict__ ao)
{
    const int b = blockIdx.z, h = blockIdx.y, q0 = blockIdx.x * 32;
    const int tid = threadIdx.x;
    __shared__ __align__(16) float Kt[32 * 212];   // Kt[d][j]; later overlaid by Ss[j][q]
    __shared__ __align__(16) float Vs[K_ * 32];    // Vs[j][d]
    __shared__ __align__(16) float Qt[32 * 36];    // Qt[d][q]
    __shared__ __align__(16) float Ored[4 * 32 * 32];
    __shared__ float red[8 * 32];
    __shared__ float inv[32];

    const float4* kg = (const float4*)(ws + OFF_KG + ((b * H_ + h) * K_) * HD_);
    const float4* vg = (const float4*)(ws + OFF_VG + ((b * H_ + h) * K_) * HD_);

    for (int i = tid; i < K_ * 8; i += 256) ((float4*)Vs)[i] = vg[i];
    for (int i = tid; i < K_ * 8; i += 256) {
        const int j = i >> 3, dc = i & 7;
        float4 kv = kg[i];
        Kt[(dc*4+0)*212 + j] = kv.x;
        Kt[(dc*4+1)*212 + j] = kv.y;
        Kt[(dc*4+2)*212 + j] = kv.z;
        Kt[(dc*4+3)*212 + j] = kv.w;
    }
    {
        const int q = tid >> 3, dc = tid & 7;
        float4 qv = *(const float4*)(ws + OFF_Q + (size_t)(b * S_ + q0 + q) * D_ + h * HD_ + dc * 4);
        Qt[(dc*4+0)*36 + q] = qv.x;
        Qt[(dc*4+1)*36 + q] = qv.y;
        Qt[(dc*4+2)*36 + q] = qv.z;
        Qt[(dc*4+3)*36 + q] = qv.w;
    }
    __syncthreads();

    // ---- scores: virtual threads w = p*256+tid; jg in [0,51), qg in [0,8) ----
    // acc[jj] is a float4 over 4 q's. exp applied in-register (scores bounded, no max needed:
    // identical math to softmax-with-max up to rounding since exp(s-m)/sum = exp(s)/sum).
    float4 e0[4], e1[4];
    {
        const int jg = tid >> 3, qg = tid & 7;
        float4 a0 = {0,0,0,0}, a1 = {0,0,0,0}, a2 = {0,0,0,0}, a3 = {0,0,0,0};
        #pragma unroll 8
        for (int d = 0; d < 32; ++d) {
            float4 kf = *(const float4*)&Kt[d*212 + jg*4];
            float4 qf = *(const float4*)&Qt[d*36 + qg*4];
            a0.x += kf.x*qf.x; a0.y += kf.x*qf.y; a0.z += kf.x*qf.z; a0.w += kf.x*qf.w;
            a1.x += kf.y*qf.x; a1.y += kf.y*qf.y; a1.z += kf.y*qf.z; a1.w += kf.y*qf.w;
            a2.x += kf.z*qf.x; a2.y += kf.z*qf.y; a2.z += kf.z*qf.z; a2.w += kf.z*qf.w;
            a3.x += kf.w*qf.x; a3.y += kf.w*qf.y; a3.z += kf.w*qf.z; a3.w += kf.w*qf.w;
        }
        e0[0].x = __expf(a0.x*SCALE_); e0[0].y = __expf(a0.y*SCALE_); e0[0].z = __expf(a0.z*SCALE_); e0[0].w = __expf(a0.w*SCALE_);
        e0[1].x = __expf(a1.x*SCALE_); e0[1].y = __expf(a1.y*SCALE_); e0[1].z = __expf(a1.z*SCALE_); e0[1].w = __expf(a1.w*SCALE_);
        e0[2].x = __expf(a2.x*SCALE_); e0[2].y = __expf(a2.y*SCALE_); e0[2].z = __expf(a2.z*SCALE_); e0[2].w = __expf(a2.w*SCALE_);
        e0[3].x = __expf(a3.x*SCALE_); e0[3].y = __expf(a3.y*SCALE_); e0[3].z = __expf(a3.z*SCALE_); e0[3].w = __expf(a3.w*SCALE_);
    }
    if (tid < 152) {
        const int w = 256 + tid;
        const int jg = w >> 3, qg = w & 7;
        float4 a0 = {0,0,0,0}, a1 = {0,0,0,0}, a2 = {0,0,0,0}, a3 = {0,0,0,0};
        #pragma unroll 8
        for (int d = 0; d < 32; ++d) {
            float4 kf = *(const float4*)&Kt[d*212 + jg*4];
            float4 qf = *(const float4*)&Qt[d*36 + qg*4];
            a0.x += kf.x*qf.x; a0.y += kf.x*qf.y; a0.z += kf.x*qf.z; a0.w += kf.x*qf.w;
            a1.x += kf.y*qf.x; a1.y += kf.y*qf.y; a1.z += kf.y*qf.z; a1.w += kf.y*qf.w;
            a2.x += kf.z*qf.x; a2.y += kf.z*qf.y; a2.z += kf.z*qf.z; a2.w += kf.z*qf.w;
            a3.x += kf.w*qf.x; a3.y += kf.w*qf.y; a3.z += kf.w*qf.z; a3.w += kf.w*qf.w;
        }
        e1[0].x = __expf(a0.x*SCALE_); e1[0].y = __expf(a0.y*SCALE_); e1[0].z = __expf(a0.z*SCALE_); e1[0].w = __expf(a0.w*SCALE_);
        e1[1].x = __expf(a1.x*SCALE_); e1[1].y = __expf(a1.y*SCALE_); e1[1].z = __expf(a1.z*SCALE_); e1[1].w = __expf(a1.w*SCALE_);
        e1[2].x = __expf(a2.x*SCALE_); e1[2].y = __expf(a2.y*SCALE_); e1[2].z = __expf(a2.z*SCALE_); e1[2].w = __expf(a2.w*SCALE_);
        e1[3].x = __expf(a3.x*SCALE_); e1[3].y = __expf(a3.y*SCALE_); e1[3].z = __expf(a3.z*SCALE_); e1[3].w = __expf(a3.w*SCALE_);
    }
    __syncthreads();   // all Kt reads complete before overlay

    float* Ss = Kt;    // Ss[j*32 + q], 6528 floats <= Kt's 6784
    {
        const int jg = tid >> 3, qg = tid & 7;
        *(float4*)&Ss[(jg*4+0)*32 + qg*4] = e0[0];
        *(float4*)&Ss[(jg*4+1)*32 + qg*4] = e0[1];
        *(float4*)&Ss[(jg*4+2)*32 + qg*4] = e0[2];
        *(float4*)&Ss[(jg*4+3)*32 + qg*4] = e0[3];
    }
    if (tid < 152) {
        const int w = 256 + tid;
        const int jg = w >> 3, qg = w & 7;
        *(float4*)&Ss[(jg*4+0)*32 + qg*4] = e1[0];
        *(float4*)&Ss[(jg*4+1)*32 + qg*4] = e1[1];
        *(float4*)&Ss[(jg*4+2)*32 + qg*4] = e1[2];
        *(float4*)&Ss[(jg*4+3)*32 + qg*4] = e1[3];
    }
    __syncthreads();

    // ---- softmax denominator ----
    {
        const int q = tid & 31, l = tid >> 5;
        float s = 0.0f;
        const int nt = (l < 4) ? 26 : 25;
        for (int t = 0; t < nt; ++t) s += Ss[(l + 8*t)*32 + q];
        red[l*32 + q] = s;
    }
    __syncthreads();
    if (tid < 32) {
        float s = 0.0f;
        #pragma unroll
        for (int l = 0; l < 8; ++l) s += red[l*32 + tid];
        inv[tid] = 1.0f / s;
    }
    __syncthreads();

    // ---- PV: wave w handles j in [51w, 51w+51); thread=(qg,dg) covers 4q x 4d ----
    {
        const int wv = tid >> 6, lane = tid & 63;
        const int qg = lane >> 3, dg = lane & 7;
        float4 c0 = {0,0,0,0}, c1 = {0,0,0,0}, c2 = {0,0,0,0}, c3 = {0,0,0,0};
        const int j0 = wv * 51;
        for (int j = j0; j < j0 + 51; ++j) {
            float4 sf = *(const float4*)&Ss[j*32 + qg*4];
            float4 vf = *(const float4*)&Vs[j*32 + dg*4];
            c0.x += sf.x*vf.x; c0.y += sf.x*vf.y; c0.z += sf.x*vf.z; c0.w += sf.x*vf.w;
            c1.x += sf.y*vf.x; c1.y += sf.y*vf.y; c1.z += sf.y*vf.z; c1.w += sf.y*vf.w;
            c2.x += sf.z*vf.x; c2.y += sf.z*vf.y; c2.z += sf.z*vf.z; c2.w += sf.z*vf.w;
            c3.x += sf.w*vf.x; c3.y += sf.w*vf.y; c3.z += sf.w*vf.z; c3.w += sf.w*vf.w;
        }
        *(float4*)&Ored[wv*1024 + (qg*4+0)*32 + dg*4] = c0;
        *(float4*)&Ored[wv*1024 + (qg*4+1)*32 + dg*4] = c1;
        *(float4*)&Ored[wv*1024 + (qg*4+2)*32 + dg*4] = c2;
        *(float4*)&Ored[wv*1024 + (qg*4+3)*32 + dg*4] = c3;
    }
    __syncthreads();
    {
        const int q = tid >> 3, dg = tid & 7;
        float4 o = {0,0,0,0};
        #pragma unroll
        for (int w = 0; w < 4; ++w) {
            float4 t = *(const float4*)&Ored[w*1024 + q*32 + dg*4];
            o.x += t.x; o.y += t.y; o.z += t.z; o.w += t.w;
        }
        const float iv = inv[q];
        float4 r; r.x = o.x*iv; r.y = o.y*iv; r.z = o.z*iv; r.w = o.w*iv;
        *(float4*)(ao + (size_t)(b * S_ + q0 + q) * D_ + h * HD_ + dg * 4) = r;
    }
}

extern "C" void kernel_launch(void* const* d_in, const int* in_sizes, int n_in,
                              void* d_out, int out_size, void* d_ws, size_t ws_size,
                              hipStream_t stream)
{
    const float* x     = (const float*)d_in[0];
    const float* w_in  = (const float*)d_in[1];
    const float* b_in  = (const float*)d_in[2];
    const float* w_out = (const float*)d_in[3];
    const float* b_out = (const float*)d_in[4];
    const float* gw1   = (const float*)d_in[5];
    const float* gb1   = (const float*)d_in[6];
    const float* gw2   = (const float*)d_in[7];
    // d_in[8] = gate_b2: constant inside monotone sigmoid -> doesn't affect top-k

    float* ws = (float*)d_ws;
    int* flags = (int*)(ws + OFF_FLAGS);
    int* kidx  = (int*)(ws + OFF_KIDX);
    float* out = (float*)d_out;

    gate_kernel<<<B_ * S_ / 8, 256, 0, stream>>>(x, gw1, gb1, gw2, ws);
    rank_kernel<<<B_ * 8, 256, 0, stream>>>(ws + OFF_IMP, flags);
    emit_kernel<<<B_, 256, 0, stream>>>(flags, kidx);
    kv_kernel<<<dim3(51, B_), 256, 0, stream>>>(x, w_in, b_in, ws, kidx);
    // Q = x @ w_in[0:256]^T + b_in[0:256]
    gemm_kernel<<<dim3(B_ * S_ / 64, D_ / 64), 256, 0, stream>>>(x, w_in, b_in, ws + OFF_Q);
    attn_kernel<<<dim3(S_ / 32, H_, B_), 256, 0, stream>>>(ws, ws + OFF_AO);
    // out = AO @ w_out^T + b_out
    gemm_kernel<<<dim3(B_ * S_ / 64, D_ / 64), 256, 0, stream>>>(ws + OFF_AO, w_out, b_out, out);
}